// Round 15
// baseline (163.488 us; speedup 1.0000x reference)
//
#include <hip/hip_runtime.h>

#define B_ 2
#define S_ 2048
#define D_ 1024
#define H_ 16
#define DH_ 64
#define WIN_ 256
#define VTS 2080   // Vt row stride (elements): 4KB+64B breaks L1 set-aliasing

typedef __attribute__((ext_vector_type(8))) short bf16x8;
typedef __attribute__((ext_vector_type(4))) float f32x4;
typedef unsigned short u16;

#define MFMA(a, b, c) __builtin_amdgcn_mfma_f32_16x16x32_bf16((a), (b), (c), 0, 0, 0)

__device__ __forceinline__ u16 f2b(float f) {
  unsigned int u = __float_as_uint(f);
  u += 0x7fffu + ((u >> 16) & 1u);
  return (u16)(u >> 16);
}

__device__ __forceinline__ float b2f(u16 b) {
  return __uint_as_float(((unsigned int)b) << 16);
}

// RTNE pack of two f32 into packed bf16x2 — single VALU op (kept from R21, neutral).
__device__ __forceinline__ unsigned int pkbf(float lo, float hi) {
  unsigned int r;
  asm("v_cvt_pk_bf16_f32 %0, %1, %2" : "=v"(r) : "v"(lo), "v"(hi));
  return r;
}

__device__ __forceinline__ void async_cp16(const void* g, void* l) {
  __builtin_amdgcn_global_load_lds(
      (const __attribute__((address_space(1))) void*)g,
      (__attribute__((address_space(3))) void*)l, 16, 0, 0);
}

// ------- prep: x fp32->bf16 convert (grid-stride) + weight transpose -------
__global__ void k_prep(const float* __restrict__ x,
                       const float* __restrict__ wq, const float* __restrict__ wk,
                       const float* __restrict__ wv, const float* __restrict__ wo,
                       u16* __restrict__ xb, u16* __restrict__ wqkvt, u16* __restrict__ wot) {
  __shared__ float tile[64][65];
  const int bx = blockIdx.x;
  const int t = threadIdx.x;
  if (bx < 1024) {
    const int t0 = (bx * 256 + t) * 4;
#pragma unroll
    for (int it = 0; it < 4; it++) {
      int i = t0 + it * 1048576;   // 1024 blocks * 256 thr * 4 elem
      float4 v = *(const float4*)(x + i);
      ushort4 o;
      o.x = f2b(v.x); o.y = f2b(v.y); o.z = f2b(v.z); o.w = f2b(v.w);
      *(ushort4*)(xb + i) = o;
    }
    return;
  }
  const int tb = bx - 1024;
  const int z = tb >> 8, rest = tb & 255;
  const float* W = z == 0 ? wq : z == 1 ? wk : z == 2 ? wv : wo;
  u16* T = z < 3 ? wqkvt + (size_t)z * 1024 * 1024 : wot;
  const int bn = (rest & 15) * 64;   // col block of W = row block of T
  const int bk = (rest >> 4) * 64;   // row block of W
  const int r = t >> 4;
  const int c = (t & 15) * 4;
#pragma unroll
  for (int i = 0; i < 4; i++) {
    float4 v = *(const float4*)(W + (size_t)(bk + r + i * 16) * D_ + bn + c);
    tile[c + 0][r + i * 16] = v.x;
    tile[c + 1][r + i * 16] = v.y;
    tile[c + 2][r + i * 16] = v.z;
    tile[c + 3][r + i * 16] = v.w;
  }
  __syncthreads();
  const int n = t >> 2, seg = (t & 3) * 16;
  __align__(16) u16 tmp[16];
#pragma unroll
  for (int u = 0; u < 16; u++) tmp[u] = f2b(tile[n][seg + u]);
  uint4* dst = (uint4*)(T + (size_t)(bn + n) * D_ + bk + seg);
  dst[0] = ((uint4*)tmp)[0];
  dst[1] = ((uint4*)tmp)[1];
}

// ---------------- 128x128 GEMM core, BK=64, XOR bank swizzle ----------------
// R23: compiler-safe L2-warming prefetch — plain dword loads of K-step t+1's
// staging lines issued right after the barrier (uses placed after the MFMA
// region; kept live via empty asm at kernel end). Compiler tracks vmcnt, so
// no R22-style untracked-register hazard. Cold cross-XCD lines (~600-900cy)
// arrive in local L2 under t's compute; t+1's global_load_lds then hits L2.
__device__ __forceinline__ unsigned gemm_core128(const u16* __restrict__ Ag,
                                                 const u16* __restrict__ Btg,
                                                 u16* As, u16* Bs, f32x4 (&acc)[4][4],
                                                 int m0, int n0) {
  const int tid = threadIdx.x;
  const int w = tid >> 6, lane = tid & 63;
  const int quad = lane >> 4, l15 = lane & 15;
  const int wm = (w & 1) * 64, wn = (w >> 1) * 64;
  const int rowa = tid >> 3;                       // 0..31
  const int colsw = (((tid & 7) ^ (rowa & 7)) * 8);
  const u16* ap = Ag + (size_t)(m0 + rowa) * D_ + colsw;
  const u16* bp = Btg + (size_t)(n0 + rowa) * D_ + colsw;
  u16* As0 = As + w * 512;
  u16* Bs0 = Bs + w * 512;
  const int c0 = ((quad * 8) ^ ((l15 & 7) * 8));
  unsigned psum = 0;
  for (int kb = 0; kb < D_; kb += 64) {
#pragma unroll
    for (int i = 0; i < 4; i++) {
      async_cp16(ap + kb + (size_t)(i * 32) * D_, As0 + i * 2048);
      async_cp16(bp + kb + (size_t)(i * 32) * D_, Bs0 + i * 2048);
    }
    __syncthreads();
    // issue t+1 prefetch loads early (results consumed after the MFMA region)
    unsigned pf[8];
    const bool more = kb + 64 < D_;
    if (more) {
#pragma unroll
      for (int i = 0; i < 4; i++) {
        pf[i]     = *(const unsigned*)(ap + kb + 64 + (size_t)(i * 32) * D_);
        pf[4 + i] = *(const unsigned*)(bp + kb + 64 + (size_t)(i * 32) * D_);
      }
    }
#pragma unroll
    for (int kh = 0; kh < 2; kh++) {
      const int c = c0 ^ (kh * 32);
      bf16x8 af[4], bfr[4];
#pragma unroll
      for (int i = 0; i < 4; i++) af[i] = *(const bf16x8*)&As[(wm + i * 16 + l15) * 64 + c];
#pragma unroll
      for (int j = 0; j < 4; j++) bfr[j] = *(const bf16x8*)&Bs[(wn + j * 16 + l15) * 64 + c];
#pragma unroll
      for (int i = 0; i < 4; i++)
#pragma unroll
        for (int j = 0; j < 4; j++) acc[i][j] = MFMA(af[i], bfr[j], acc[i][j]);
    }
    if (more) {
#pragma unroll
      for (int i = 0; i < 8; i++) psum += pf[i];
    }
    __syncthreads();
  }
  return psum;
}

// -------- fused QKV GEMM over N=3072; Q,K -> [B,S,D]; V -> [B,H,DH,VTS] --------
__global__ __launch_bounds__(256, 3) void k_gemm_qkv(
    const u16* __restrict__ xb, const u16* __restrict__ wqkvt,
    const float* __restrict__ bq, const float* __restrict__ bk_, const float* __restrict__ bv,
    u16* __restrict__ Qg, u16* __restrict__ Kg, u16* __restrict__ Vt) {
  __shared__ __align__(16) u16 smem[17408];   // stage: 2x8192; epilogue: 128x136
  u16* As = smem;
  u16* Bs = smem + 8192;
  const int L = blockIdx.x;
  const int xcd = L & 7, slot = L >> 3;            // slot 0..95
  const int mblk = (xcd >> 1) * 8 + (slot & 7);    // 0..31
  const int nblk = (xcd & 1) * 12 + (slot >> 3);   // 0..23
  const int n0 = nblk * 128, m0 = mblk * 128;
  const int z = n0 >> 10;
  const float* bias = z == 0 ? bq : z == 1 ? bk_ : bv;
  f32x4 acc[4][4] = {};
  unsigned psum = gemm_core128(xb, wqkvt, As, Bs, acc, m0, n0);
  asm volatile("" :: "v"(psum));   // keep prefetch loads live (rule #17); no memory op

  const int tid = threadIdx.x;
  const int w = tid >> 6, lane = tid & 63;
  const int quad = lane >> 4, l15 = lane & 15;
  const int wm = (w & 1) * 64, wn = (w >> 1) * 64;
  const int nloc = n0 & 1023;
  float biasv[4];
#pragma unroll
  for (int j = 0; j < 4; j++) biasv[j] = bias[nloc + wn + j * 16 + l15];
  const int b_ = m0 >> 11, sb = m0 & 2047;
  // Q pre-scale folds 1/sqrt(DH) and log2(e) so attention uses raw exp2.
  const float scale = z == 0 ? 0.125f * 1.44269504f : 1.0f;
  const int row = tid >> 4, ch = tid & 15;

  if (z < 2) {
    // C-layout -> LDS (padded stride 136) -> coalesced row-major store
#pragma unroll
    for (int j = 0; j < 4; j++)
#pragma unroll
      for (int i = 0; i < 4; i++)
#pragma unroll
        for (int r = 0; r < 4; r++)
          smem[(wm + i * 16 + quad * 4 + r) * 136 + wn + j * 16 + l15] =
              f2b((acc[i][j][r] + biasv[j]) * scale);
    __syncthreads();
    u16* OG = z == 0 ? Qg : Kg;
#pragma unroll
    for (int it = 0; it < 8; it++) {
      int rr = row + it * 16;
      bf16x8 v = *(const bf16x8*)&smem[rr * 136 + ch * 8];
      *(bf16x8*)(OG + (size_t)(m0 + rr) * D_ + nloc + ch * 8) = v;
    }
  } else {
    // write transposed into LDS: Ct[n_local][m_local]
#pragma unroll
    for (int j = 0; j < 4; j++)
#pragma unroll
      for (int i = 0; i < 4; i++)
#pragma unroll
        for (int r = 0; r < 4; r++)
          smem[(wn + j * 16 + l15) * 136 + wm + i * 16 + quad * 4 + r] =
              f2b(acc[i][j][r] + biasv[j]);
    __syncthreads();
#pragma unroll
    for (int it = 0; it < 8; it++) {
      int nn = nloc + row + it * 16;
      int h = nn >> 6, dh = nn & 63;
      bf16x8 v = *(const bf16x8*)&smem[(row + it * 16) * 136 + ch * 8];
      *(bf16x8*)(Vt + ((size_t)(b_ * H_ + h) * DH_ + dh) * VTS + sb + ch * 8) = v;
    }
  }
}

// ---------- output projection: 64x128 tiles, BK=128 (32 MFMA/barrier) ----------
__global__ __launch_bounds__(256, 2) void k_gemm_out(
    const u16* __restrict__ Ab, const u16* __restrict__ wot,
    const float* __restrict__ bo, float* __restrict__ out) {
  __shared__ __align__(16) u16 smem[24576];   // A 64x128 + B 128x128; epilogue 64x136
  u16* As = smem;
  u16* Bs = smem + 8192;
  const int L = blockIdx.x;
  const int xcd = L & 7, slot = L >> 3;        // slot 0..63
  const int mblk = xcd * 8 + (slot & 7);       // 0..63
  const int nblk = slot >> 3;                  // 0..7
  const int n0 = nblk * 128, m0 = mblk * 64;
  const int tid = threadIdx.x;
  const int w = tid >> 6, lane = tid & 63;
  const int quad = lane >> 4, l15 = lane & 15;
  const int wn = w * 32;
  const int rowa = tid >> 4;                   // 0..15
  const int gg = (tid & 15) ^ rowa;
  const u16* ap = Ab + (size_t)(m0 + rowa) * D_ + gg * 8;
  const u16* bp = wot + (size_t)(n0 + rowa) * D_ + gg * 8;
  u16* As0 = As + w * 512;
  u16* Bs0 = Bs + w * 512;
  f32x4 acc[4][2] = {};
  for (int kb = 0; kb < D_; kb += 128) {
#pragma unroll
    for (int i = 0; i < 4; i++)
      async_cp16(ap + kb + (size_t)(i * 16) * D_, As0 + i * 2048);
#pragma unroll
    for (int i = 0; i < 8; i++)
      async_cp16(bp + kb + (size_t)(i * 16) * D_, Bs0 + i * 2048);
    __syncthreads();
#pragma unroll
    for (int kh = 0; kh < 4; kh++) {
      const int cs = (((quad + 4 * kh) ^ l15) * 8);
      bf16x8 af[4], bfr[2];
#pragma unroll
      for (int i = 0; i < 4; i++) af[i] = *(const bf16x8*)&As[(i * 16 + l15) * 128 + cs];
#pragma unroll
      for (int j = 0; j < 2; j++) bfr[j] = *(const bf16x8*)&Bs[(wn + j * 16 + l15) * 128 + cs];
#pragma unroll
      for (int i = 0; i < 4; i++)
#pragma unroll
        for (int j = 0; j < 2; j++) acc[i][j] = MFMA(af[i], bfr[j], acc[i][j]);
    }
    __syncthreads();
  }
  float biasv[2];
#pragma unroll
  for (int j = 0; j < 2; j++) biasv[j] = bo[n0 + wn + j * 16 + l15];
#pragma unroll
  for (int j = 0; j < 2; j++)
#pragma unroll
    for (int i = 0; i < 4; i++)
#pragma unroll
      for (int r = 0; r < 4; r++)
        smem[(i * 16 + quad * 4 + r) * 136 + wn + j * 16 + l15] = f2b(acc[i][j][r] + biasv[j]);
  __syncthreads();
  const int row = tid >> 4, ch = tid & 15;
#pragma unroll
  for (int it = 0; it < 4; it++) {
    int rr = row + it * 16;
    bf16x8 v = *(const bf16x8*)&smem[rr * 136 + ch * 8];
    float4 f0, f1;
    f0.x = b2f((u16)v[0]); f0.y = b2f((u16)v[1]); f0.z = b2f((u16)v[2]); f0.w = b2f((u16)v[3]);
    f1.x = b2f((u16)v[4]); f1.y = b2f((u16)v[5]); f1.z = b2f((u16)v[6]); f1.w = b2f((u16)v[7]);
    float* dst = out + (size_t)(m0 + rr) * D_ + n0 + ch * 8;
    *(float4*)dst = f0;
    *(float4*)(dst + 4) = f1;
  }
}

// ---------------- windowed flash attention, QBLK=32 per wave ----------------
// R18 (validated): 32 queries/wave as two 16-query sub-tiles sharing one K/V walk.
// R15 XCD pinning kept; R21 cvt_pk pack kept (neutral, shorter).
__global__ __launch_bounds__(256, 2) void k_attn(
    const u16* __restrict__ Qg, const u16* __restrict__ Kg,
    const u16* __restrict__ Vt, u16* __restrict__ Ab) {
  __shared__ __align__(16) u16 Plds[4][32 * 72];
  const int tid = threadIdx.x;
  const int w = tid >> 6, lane = tid & 63;
  const int quad = lane >> 4, l15 = lane & 15;
  const int lid = blockIdx.x;
  const int xcd = lid & 7, slot = lid >> 3;   // slot 0..63
  const int bh = xcd * 4 + (slot & 3);        // 4 bh per XCD
  const int qb = slot >> 2;                   // 0..15
  const int qw = qb * 128 + w * 32;           // wave's 32-query base (mult of 32)
  const int b_ = bh >> 4, h = bh & 15;

  // Q fragments: sub-tile A = queries qw+l15, B = qw+16+l15 (pre-scaled)
  const u16* QbaseA = Qg + (size_t)(b_ * S_ + qw + l15) * D_ + h * DH_ + quad * 8;
  bf16x8 aq0 = *(const bf16x8*)QbaseA;
  bf16x8 aq1 = *(const bf16x8*)(QbaseA + 32);
  const u16* QbaseB = QbaseA + (size_t)16 * D_;
  bf16x8 bq0 = *(const bf16x8*)QbaseB;
  bf16x8 bq1 = *(const bf16x8*)(QbaseB + 32);

  float lrA = 0.f, lrB = 0.f;
  f32x4 OA[4] = {}, OB[4] = {};

  const u16* Kb = Kg + (size_t)b_ * S_ * D_ + h * DH_ + quad * 8;
  const u16* Vb = Vt + (size_t)bh * DH_ * VTS + (size_t)l15 * VTS + quad * 8;
  const int klo = qw >= WIN_ ? qw - WIN_ : 0;   // qw mult of 32 -> aligned
  const int qA = qw + l15, qB = qA + 16;
  const int qwB = qw + 16;
  const int srcA = l15 + ((quad & 1) ? 32 : 0);
  const int srcB = srcA + 16;

  bf16x8 k00, k01, k10, k11, v0, v1, v2, v3;
  {
    const u16* Kt0 = Kb + (size_t)(klo + l15) * D_;
    k00 = *(const bf16x8*)Kt0;
    k01 = *(const bf16x8*)(Kt0 + 32);
    k10 = *(const bf16x8*)(Kt0 + (size_t)16 * D_);
    k11 = *(const bf16x8*)(Kt0 + (size_t)16 * D_ + 32);
    const u16* Vt0 = Vb + klo;
    v0 = *(const bf16x8*)(Vt0);
    v1 = *(const bf16x8*)(Vt0 + (size_t)16 * VTS);
    v2 = *(const bf16x8*)(Vt0 + (size_t)32 * VTS);
    v3 = *(const bf16x8*)(Vt0 + (size_t)48 * VTS);
  }

  for (int k0 = klo;;) {
    const int kn = k0 + 32;
    const bool more = kn <= qw;   // last tile starts at k0 == qw (covers qw..qw+31)
    bf16x8 nk00, nk01, nk10, nk11, nv0, nv1, nv2, nv3;
    if (more) {
      const u16* Kt0 = Kb + (size_t)(kn + l15) * D_;
      nk00 = *(const bf16x8*)Kt0;
      nk01 = *(const bf16x8*)(Kt0 + 32);
      nk10 = *(const bf16x8*)(Kt0 + (size_t)16 * D_);
      nk11 = *(const bf16x8*)(Kt0 + (size_t)16 * D_ + 32);
      const u16* Vt0 = Vb + kn;
      nv0 = *(const bf16x8*)(Vt0);
      nv1 = *(const bf16x8*)(Vt0 + (size_t)16 * VTS);
      nv2 = *(const bf16x8*)(Vt0 + (size_t)32 * VTS);
      nv3 = *(const bf16x8*)(Vt0 + (size_t)48 * VTS);
    }

    // wave-uniform sub-tile activity for this k-tile
    const bool computeA = (k0 <= qw + 15);              // any key <= an A query
    const bool computeB = (k0 + 31 >= qwB - WIN_);      // any key in B's window

    if (computeA) {
      f32x4 s0 = {0.f, 0.f, 0.f, 0.f}, s1 = {0.f, 0.f, 0.f, 0.f};
      __builtin_amdgcn_s_setprio(1);
      s0 = MFMA(k00, aq0, s0);
      s0 = MFMA(k01, aq1, s0);
      s1 = MFMA(k10, aq0, s1);
      s1 = MFMA(k11, aq1, s1);
      __builtin_amdgcn_s_setprio(0);
      const bool interior = (k0 >= qw + 15 - WIN_) && (k0 + 31 <= qw);
      float e[8];
      if (interior) {
#pragma unroll
        for (int r = 0; r < 4; r++) {
          float p0 = __builtin_amdgcn_exp2f(s0[r]);
          float p1 = __builtin_amdgcn_exp2f(s1[r]);
          e[r] = p0; e[4 + r] = p1;
          lrA += p0 + p1;
        }
      } else {
#pragma unroll
        for (int r = 0; r < 4; r++) {
          int key0 = k0 + quad * 4 + r;
          int key1 = key0 + 16;
          float p0 = (key0 <= qA && key0 + WIN_ >= qA) ? __builtin_amdgcn_exp2f(s0[r]) : 0.f;
          float p1 = (key1 <= qA && key1 + WIN_ >= qA) ? __builtin_amdgcn_exp2f(s1[r]) : 0.f;
          e[r] = p0; e[4 + r] = p1;
          lrA += p0 + p1;
        }
      }
      unsigned int s0p01 = pkbf(e[0], e[1]);
      unsigned int s0p23 = pkbf(e[2], e[3]);
      unsigned int s1p01 = pkbf(e[4], e[5]);
      unsigned int s1p23 = pkbf(e[6], e[7]);
      unsigned int a0 = (unsigned)__shfl((int)s0p01, srcA);
      unsigned int a1 = (unsigned)__shfl((int)s0p23, srcA);
      unsigned int a2 = (unsigned)__shfl((int)s0p01, srcB);
      unsigned int a3 = (unsigned)__shfl((int)s0p23, srcB);
      unsigned int c0 = (unsigned)__shfl((int)s1p01, srcA);
      unsigned int c1 = (unsigned)__shfl((int)s1p23, srcA);
      unsigned int c2 = (unsigned)__shfl((int)s1p01, srcB);
      unsigned int c3 = (unsigned)__shfl((int)s1p23, srcB);
      union { unsigned int u[4]; bf16x8 v; } pf;
      const bool lo = quad < 2;
      pf.u[0] = lo ? a0 : c0;
      pf.u[1] = lo ? a1 : c1;
      pf.u[2] = lo ? a2 : c2;
      pf.u[3] = lo ? a3 : c3;
      __builtin_amdgcn_s_setprio(1);
      OA[0] = MFMA(v0, pf.v, OA[0]);
      OA[1] = MFMA(v1, pf.v, OA[1]);
      OA[2] = MFMA(v2, pf.v, OA[2]);
      OA[3] = MFMA(v3, pf.v, OA[3]);
      __builtin_amdgcn_s_setprio(0);
    }

    if (computeB) {
      f32x4 s0 = {0.f, 0.f, 0.f, 0.f}, s1 = {0.f, 0.f, 0.f, 0.f};
      __builtin_amdgcn_s_setprio(1);
      s0 = MFMA(k00, bq0, s0);
      s0 = MFMA(k01, bq1, s0);
      s1 = MFMA(k10, bq0, s1);
      s1 = MFMA(k11, bq1, s1);
      __builtin_amdgcn_s_setprio(0);
      const bool interior = (k0 >= qwB + 15 - WIN_) && (k0 + 31 <= qwB);
      float e[8];
      if (interior) {
#pragma unroll
        for (int r = 0; r < 4; r++) {
          float p0 = __builtin_amdgcn_exp2f(s0[r]);
          float p1 = __builtin_amdgcn_exp2f(s1[r]);
          e[r] = p0; e[4 + r] = p1;
          lrB += p0 + p1;
        }
      } else {
#pragma unroll
        for (int r = 0; r < 4; r++) {
          int key0 = k0 + quad * 4 + r;
          int key1 = key0 + 16;
          float p0 = (key0 <= qB && key0 + WIN_ >= qB) ? __builtin_amdgcn_exp2f(s0[r]) : 0.f;
          float p1 = (key1 <= qB && key1 + WIN_ >= qB) ? __builtin_amdgcn_exp2f(s1[r]) : 0.f;
          e[r] = p0; e[4 + r] = p1;
          lrB += p0 + p1;
        }
      }
      unsigned int s0p01 = pkbf(e[0], e[1]);
      unsigned int s0p23 = pkbf(e[2], e[3]);
      unsigned int s1p01 = pkbf(e[4], e[5]);
      unsigned int s1p23 = pkbf(e[6], e[7]);
      unsigned int a0 = (unsigned)__shfl((int)s0p01, srcA);
      unsigned int a1 = (unsigned)__shfl((int)s0p23, srcA);
      unsigned int a2 = (unsigned)__shfl((int)s0p01, srcB);
      unsigned int a3 = (unsigned)__shfl((int)s0p23, srcB);
      unsigned int c0 = (unsigned)__shfl((int)s1p01, srcA);
      unsigned int c1 = (unsigned)__shfl((int)s1p23, srcA);
      unsigned int c2 = (unsigned)__shfl((int)s1p01, srcB);
      unsigned int c3 = (unsigned)__shfl((int)s1p23, srcB);
      union { unsigned int u[4]; bf16x8 v; } pf;
      const bool lo = quad < 2;
      pf.u[0] = lo ? a0 : c0;
      pf.u[1] = lo ? a1 : c1;
      pf.u[2] = lo ? a2 : c2;
      pf.u[3] = lo ? a3 : c3;
      __builtin_amdgcn_s_setprio(1);
      OB[0] = MFMA(v0, pf.v, OB[0]);
      OB[1] = MFMA(v1, pf.v, OB[1]);
      OB[2] = MFMA(v2, pf.v, OB[2]);
      OB[3] = MFMA(v3, pf.v, OB[3]);
      __builtin_amdgcn_s_setprio(0);
    }

    if (!more) break;
    k00 = nk00; k01 = nk01; k10 = nk10; k11 = nk11;
    v0 = nv0; v1 = nv1; v2 = nv2; v3 = nv3;
    k0 = kn;
  }

  // per-quad partial sums -> full row sums (same l15 across quads)
  lrA += __shfl_xor(lrA, 16);
  lrA += __shfl_xor(lrA, 32);
  lrB += __shfl_xor(lrB, 16);
  lrB += __shfl_xor(lrB, 32);
  const float invA = 1.0f / lrA;
  const float invB = 1.0f / lrB;

  // epilogue: 32 rows per wave (A -> rows 0..15, B -> rows 16..31)
  u16* P = &Plds[w][0];
#pragma unroll
  for (int j = 0; j < 4; j++)
#pragma unroll
    for (int r = 0; r < 4; r++) {
      P[l15 * 72 + j * 16 + quad * 4 + r] = f2b(OA[j][r] * invA);
      P[(l15 + 16) * 72 + j * 16 + quad * 4 + r] = f2b(OB[j][r] * invB);
    }
#pragma unroll
  for (int it = 0; it < 2; it++) {
    int rq = (lane >> 2) + it * 16, cc = lane & 3;
    bf16x8 ov0 = *(const bf16x8*)&P[rq * 72 + cc * 16];
    bf16x8 ov1 = *(const bf16x8*)&P[rq * 72 + cc * 16 + 8];
    u16* dst = Ab + (size_t)(b_ * S_ + qw + rq) * D_ + h * DH_ + cc * 16;
    *(bf16x8*)dst = ov0;
    *(bf16x8*)(dst + 8) = ov1;
  }
}

extern "C" void kernel_launch(void* const* d_in, const int* in_sizes, int n_in,
                              void* d_out, int out_size, void* d_ws, size_t ws_size,
                              hipStream_t stream) {
  const float* x  = (const float*)d_in[0];
  const float* wq = (const float*)d_in[1];
  const float* bq = (const float*)d_in[2];
  const float* wk = (const float*)d_in[3];
  const float* bk = (const float*)d_in[4];
  const float* wv = (const float*)d_in[5];
  const float* bv = (const float*)d_in[6];
  const float* wo = (const float*)d_in[7];
  const float* bo = (const float*)d_in[8];

  char* ws = (char*)d_ws;
  const size_t MB = 1u << 20;
  u16* Qg    = (u16*)(ws + 0 * MB);    // 8 MB [B,S,D] bf16, pre-scaled
  u16* Kg    = (u16*)(ws + 8 * MB);    // 8 MB [B,S,D]
  u16* Vt    = (u16*)(ws + 16 * MB);   // 9 MB [B,H,DH,VTS] (padded stride)
  u16* Ab    = (u16*)(ws + 25 * MB);   // 8 MB [B,S,D] attention output
  u16* xb    = (u16*)(ws + 33 * MB);   // 8 MB [B*S,D]
  u16* wqkvt = (u16*)(ws + 41 * MB);   // 6 MB [3072][1024] transposed bf16
  u16* wot   = (u16*)(ws + 47 * MB);   // 2 MB [1024][1024] transposed bf16

  k_prep<<<2048, 256, 0, stream>>>(x, wq, wk, wv, wo, xb, wqkvt, wot);
  k_gemm_qkv<<<768, 256, 0, stream>>>(xb, wqkvt, bq, bk, bv, Qg, Kg, Vt);
  k_attn<<<512, 256, 0, stream>>>(Qg, Kg, Vt, Ab);
  k_gemm_out<<<512, 256, 0, stream>>>(Ab, wot, bo, (float*)d_out);
}

// Round 16
// 153.249 us; speedup vs baseline: 1.0668x; 1.0668x over previous
//
#include <hip/hip_runtime.h>

#define B_ 2
#define S_ 2048
#define D_ 1024
#define H_ 16
#define DH_ 64
#define WIN_ 256
#define VTS 2080   // Vt row stride (elements): 4KB+64B breaks L1 set-aliasing

typedef __attribute__((ext_vector_type(8))) short bf16x8;
typedef __attribute__((ext_vector_type(4))) float f32x4;
typedef unsigned short u16;

#define MFMA(a, b, c) __builtin_amdgcn_mfma_f32_16x16x32_bf16((a), (b), (c), 0, 0, 0)

__device__ __forceinline__ u16 f2b(float f) {
  unsigned int u = __float_as_uint(f);
  u += 0x7fffu + ((u >> 16) & 1u);
  return (u16)(u >> 16);
}

__device__ __forceinline__ float b2f(u16 b) {
  return __uint_as_float(((unsigned int)b) << 16);
}

// RTNE pack of two f32 into packed bf16x2 — single VALU op (kept from R21, neutral).
__device__ __forceinline__ unsigned int pkbf(float lo, float hi) {
  unsigned int r;
  asm("v_cvt_pk_bf16_f32 %0, %1, %2" : "=v"(r) : "v"(lo), "v"(hi));
  return r;
}

__device__ __forceinline__ void async_cp16(const void* g, void* l) {
  __builtin_amdgcn_global_load_lds(
      (const __attribute__((address_space(1))) void*)g,
      (__attribute__((address_space(3))) void*)l, 16, 0, 0);
}

// ------- prep: x fp32->bf16 convert (grid-stride) + weight transpose -------
__global__ void k_prep(const float* __restrict__ x,
                       const float* __restrict__ wq, const float* __restrict__ wk,
                       const float* __restrict__ wv, const float* __restrict__ wo,
                       u16* __restrict__ xb, u16* __restrict__ wqkvt, u16* __restrict__ wot) {
  __shared__ float tile[64][65];
  const int bx = blockIdx.x;
  const int t = threadIdx.x;
  if (bx < 1024) {
    const int t0 = (bx * 256 + t) * 4;
#pragma unroll
    for (int it = 0; it < 4; it++) {
      int i = t0 + it * 1048576;   // 1024 blocks * 256 thr * 4 elem
      float4 v = *(const float4*)(x + i);
      ushort4 o;
      o.x = f2b(v.x); o.y = f2b(v.y); o.z = f2b(v.z); o.w = f2b(v.w);
      *(ushort4*)(xb + i) = o;
    }
    return;
  }
  const int tb = bx - 1024;
  const int z = tb >> 8, rest = tb & 255;
  const float* W = z == 0 ? wq : z == 1 ? wk : z == 2 ? wv : wo;
  u16* T = z < 3 ? wqkvt + (size_t)z * 1024 * 1024 : wot;
  const int bn = (rest & 15) * 64;   // col block of W = row block of T
  const int bk = (rest >> 4) * 64;   // row block of W
  const int r = t >> 4;
  const int c = (t & 15) * 4;
#pragma unroll
  for (int i = 0; i < 4; i++) {
    float4 v = *(const float4*)(W + (size_t)(bk + r + i * 16) * D_ + bn + c);
    tile[c + 0][r + i * 16] = v.x;
    tile[c + 1][r + i * 16] = v.y;
    tile[c + 2][r + i * 16] = v.z;
    tile[c + 3][r + i * 16] = v.w;
  }
  __syncthreads();
  const int n = t >> 2, seg = (t & 3) * 16;
  __align__(16) u16 tmp[16];
#pragma unroll
  for (int u = 0; u < 16; u++) tmp[u] = f2b(tile[n][seg + u]);
  uint4* dst = (uint4*)(T + (size_t)(bn + n) * D_ + bk + seg);
  dst[0] = ((uint4*)tmp)[0];
  dst[1] = ((uint4*)tmp)[1];
}

// ---------------- 128x128 GEMM core, BK=64, XOR bank swizzle ----------------
__device__ __forceinline__ void gemm_core128(const u16* __restrict__ Ag, const u16* __restrict__ Btg,
                                             u16* As, u16* Bs, f32x4 (&acc)[4][4],
                                             int m0, int n0) {
  const int tid = threadIdx.x;
  const int w = tid >> 6, lane = tid & 63;
  const int quad = lane >> 4, l15 = lane & 15;
  const int wm = (w & 1) * 64, wn = (w >> 1) * 64;
  const int rowa = tid >> 3;                       // 0..31
  const int colsw = (((tid & 7) ^ (rowa & 7)) * 8);
  const u16* ap = Ag + (size_t)(m0 + rowa) * D_ + colsw;
  const u16* bp = Btg + (size_t)(n0 + rowa) * D_ + colsw;
  u16* As0 = As + w * 512;
  u16* Bs0 = Bs + w * 512;
  const int c0 = ((quad * 8) ^ ((l15 & 7) * 8));
  for (int kb = 0; kb < D_; kb += 64) {
#pragma unroll
    for (int i = 0; i < 4; i++) {
      async_cp16(ap + kb + (size_t)(i * 32) * D_, As0 + i * 2048);
      async_cp16(bp + kb + (size_t)(i * 32) * D_, Bs0 + i * 2048);
    }
    __syncthreads();
#pragma unroll
    for (int kh = 0; kh < 2; kh++) {
      const int c = c0 ^ (kh * 32);
      bf16x8 af[4], bfr[4];
#pragma unroll
      for (int i = 0; i < 4; i++) af[i] = *(const bf16x8*)&As[(wm + i * 16 + l15) * 64 + c];
#pragma unroll
      for (int j = 0; j < 4; j++) bfr[j] = *(const bf16x8*)&Bs[(wn + j * 16 + l15) * 64 + c];
#pragma unroll
      for (int i = 0; i < 4; i++)
#pragma unroll
        for (int j = 0; j < 4; j++) acc[i][j] = MFMA(af[i], bfr[j], acc[i][j]);
    }
    __syncthreads();
  }
}

// -------- fused QKV GEMM over N=3072; Q,K -> [B,S,D]; V -> [B,H,DH,VTS] --------
__global__ __launch_bounds__(256, 3) void k_gemm_qkv(
    const u16* __restrict__ xb, const u16* __restrict__ wqkvt,
    const float* __restrict__ bq, const float* __restrict__ bk_, const float* __restrict__ bv,
    u16* __restrict__ Qg, u16* __restrict__ Kg, u16* __restrict__ Vt) {
  __shared__ __align__(16) u16 smem[17408];   // stage: 2x8192; epilogue: 128x136
  u16* As = smem;
  u16* Bs = smem + 8192;
  const int L = blockIdx.x;
  const int xcd = L & 7, slot = L >> 3;            // slot 0..95
  const int mblk = (xcd >> 1) * 8 + (slot & 7);    // 0..31
  const int nblk = (xcd & 1) * 12 + (slot >> 3);   // 0..23
  const int n0 = nblk * 128, m0 = mblk * 128;
  const int z = n0 >> 10;
  const float* bias = z == 0 ? bq : z == 1 ? bk_ : bv;
  f32x4 acc[4][4] = {};
  gemm_core128(xb, wqkvt, As, Bs, acc, m0, n0);

  const int tid = threadIdx.x;
  const int w = tid >> 6, lane = tid & 63;
  const int quad = lane >> 4, l15 = lane & 15;
  const int wm = (w & 1) * 64, wn = (w >> 1) * 64;
  const int nloc = n0 & 1023;
  float biasv[4];
#pragma unroll
  for (int j = 0; j < 4; j++) biasv[j] = bias[nloc + wn + j * 16 + l15];
  const int b_ = m0 >> 11, sb = m0 & 2047;
  // Q pre-scale folds 1/sqrt(DH) and log2(e) so attention uses raw exp2.
  const float scale = z == 0 ? 0.125f * 1.44269504f : 1.0f;
  const int row = tid >> 4, ch = tid & 15;

  if (z < 2) {
    // C-layout -> LDS (padded stride 136) -> coalesced row-major store
#pragma unroll
    for (int j = 0; j < 4; j++)
#pragma unroll
      for (int i = 0; i < 4; i++)
#pragma unroll
        for (int r = 0; r < 4; r++)
          smem[(wm + i * 16 + quad * 4 + r) * 136 + wn + j * 16 + l15] =
              f2b((acc[i][j][r] + biasv[j]) * scale);
    __syncthreads();
    u16* OG = z == 0 ? Qg : Kg;
#pragma unroll
    for (int it = 0; it < 8; it++) {
      int rr = row + it * 16;
      bf16x8 v = *(const bf16x8*)&smem[rr * 136 + ch * 8];
      *(bf16x8*)(OG + (size_t)(m0 + rr) * D_ + nloc + ch * 8) = v;
    }
  } else {
    // write transposed into LDS: Ct[n_local][m_local]
#pragma unroll
    for (int j = 0; j < 4; j++)
#pragma unroll
      for (int i = 0; i < 4; i++)
#pragma unroll
        for (int r = 0; r < 4; r++)
          smem[(wn + j * 16 + l15) * 136 + wm + i * 16 + quad * 4 + r] =
              f2b(acc[i][j][r] + biasv[j]);
    __syncthreads();
#pragma unroll
    for (int it = 0; it < 8; it++) {
      int nn = nloc + row + it * 16;
      int h = nn >> 6, dh = nn & 63;
      bf16x8 v = *(const bf16x8*)&smem[(row + it * 16) * 136 + ch * 8];
      *(bf16x8*)(Vt + ((size_t)(b_ * H_ + h) * DH_ + dh) * VTS + sb + ch * 8) = v;
    }
  }
}

// ---------- output projection: 64x128 tiles, BK=128 (32 MFMA/barrier) ----------
__global__ __launch_bounds__(256, 2) void k_gemm_out(
    const u16* __restrict__ Ab, const u16* __restrict__ wot,
    const float* __restrict__ bo, float* __restrict__ out) {
  __shared__ __align__(16) u16 smem[24576];   // A 64x128 + B 128x128; epilogue 64x136
  u16* As = smem;
  u16* Bs = smem + 8192;
  const int L = blockIdx.x;
  const int xcd = L & 7, slot = L >> 3;        // slot 0..63
  const int mblk = xcd * 8 + (slot & 7);       // 0..63
  const int nblk = slot >> 3;                  // 0..7
  const int n0 = nblk * 128, m0 = mblk * 64;
  const int tid = threadIdx.x;
  const int w = tid >> 6, lane = tid & 63;
  const int quad = lane >> 4, l15 = lane & 15;
  const int wn = w * 32;
  const int rowa = tid >> 4;                   // 0..15
  const int gg = (tid & 15) ^ rowa;
  const u16* ap = Ab + (size_t)(m0 + rowa) * D_ + gg * 8;
  const u16* bp = wot + (size_t)(n0 + rowa) * D_ + gg * 8;
  u16* As0 = As + w * 512;
  u16* Bs0 = Bs + w * 512;
  f32x4 acc[4][2] = {};
  for (int kb = 0; kb < D_; kb += 128) {
#pragma unroll
    for (int i = 0; i < 4; i++)
      async_cp16(ap + kb + (size_t)(i * 16) * D_, As0 + i * 2048);
#pragma unroll
    for (int i = 0; i < 8; i++)
      async_cp16(bp + kb + (size_t)(i * 16) * D_, Bs0 + i * 2048);
    __syncthreads();
#pragma unroll
    for (int kh = 0; kh < 4; kh++) {
      const int cs = (((quad + 4 * kh) ^ l15) * 8);
      bf16x8 af[4], bfr[2];
#pragma unroll
      for (int i = 0; i < 4; i++) af[i] = *(const bf16x8*)&As[(i * 16 + l15) * 128 + cs];
#pragma unroll
      for (int j = 0; j < 2; j++) bfr[j] = *(const bf16x8*)&Bs[(wn + j * 16 + l15) * 128 + cs];
#pragma unroll
      for (int i = 0; i < 4; i++)
#pragma unroll
        for (int j = 0; j < 2; j++) acc[i][j] = MFMA(af[i], bfr[j], acc[i][j]);
    }
    __syncthreads();
  }
  float biasv[2];
#pragma unroll
  for (int j = 0; j < 2; j++) biasv[j] = bo[n0 + wn + j * 16 + l15];
#pragma unroll
  for (int j = 0; j < 2; j++)
#pragma unroll
    for (int i = 0; i < 4; i++)
#pragma unroll
      for (int r = 0; r < 4; r++)
        smem[(i * 16 + quad * 4 + r) * 136 + wn + j * 16 + l15] = f2b(acc[i][j][r] + biasv[j]);
  __syncthreads();
  const int row = tid >> 4, ch = tid & 15;
#pragma unroll
  for (int it = 0; it < 4; it++) {
    int rr = row + it * 16;
    bf16x8 v = *(const bf16x8*)&smem[rr * 136 + ch * 8];
    float4 f0, f1;
    f0.x = b2f((u16)v[0]); f0.y = b2f((u16)v[1]); f0.z = b2f((u16)v[2]); f0.w = b2f((u16)v[3]);
    f1.x = b2f((u16)v[4]); f1.y = b2f((u16)v[5]); f1.z = b2f((u16)v[6]); f1.w = b2f((u16)v[7]);
    float* dst = out + (size_t)(m0 + rr) * D_ + n0 + ch * 8;
    *(float4*)dst = f0;
    *(float4*)(dst + 4) = f1;
  }
}

// ---------------- windowed flash attention, QBLK=32 per wave ----------------
// R18 (validated): 32 queries/wave as two 16-query sub-tiles sharing one K/V walk.
// R15 XCD pinning kept; R21 cvt_pk pack kept (neutral, shorter).
__global__ __launch_bounds__(256, 2) void k_attn(
    const u16* __restrict__ Qg, const u16* __restrict__ Kg,
    const u16* __restrict__ Vt, u16* __restrict__ Ab) {
  __shared__ __align__(16) u16 Plds[4][32 * 72];
  const int tid = threadIdx.x;
  const int w = tid >> 6, lane = tid & 63;
  const int quad = lane >> 4, l15 = lane & 15;
  const int lid = blockIdx.x;
  const int xcd = lid & 7, slot = lid >> 3;   // slot 0..63
  const int bh = xcd * 4 + (slot & 3);        // 4 bh per XCD
  const int qb = slot >> 2;                   // 0..15
  const int qw = qb * 128 + w * 32;           // wave's 32-query base (mult of 32)
  const int b_ = bh >> 4, h = bh & 15;

  // Q fragments: sub-tile A = queries qw+l15, B = qw+16+l15 (pre-scaled)
  const u16* QbaseA = Qg + (size_t)(b_ * S_ + qw + l15) * D_ + h * DH_ + quad * 8;
  bf16x8 aq0 = *(const bf16x8*)QbaseA;
  bf16x8 aq1 = *(const bf16x8*)(QbaseA + 32);
  const u16* QbaseB = QbaseA + (size_t)16 * D_;
  bf16x8 bq0 = *(const bf16x8*)QbaseB;
  bf16x8 bq1 = *(const bf16x8*)(QbaseB + 32);

  float lrA = 0.f, lrB = 0.f;
  f32x4 OA[4] = {}, OB[4] = {};

  const u16* Kb = Kg + (size_t)b_ * S_ * D_ + h * DH_ + quad * 8;
  const u16* Vb = Vt + (size_t)bh * DH_ * VTS + (size_t)l15 * VTS + quad * 8;
  const int klo = qw >= WIN_ ? qw - WIN_ : 0;   // qw mult of 32 -> aligned
  const int qA = qw + l15, qB = qA + 16;
  const int qwB = qw + 16;
  const int srcA = l15 + ((quad & 1) ? 32 : 0);
  const int srcB = srcA + 16;

  bf16x8 k00, k01, k10, k11, v0, v1, v2, v3;
  {
    const u16* Kt0 = Kb + (size_t)(klo + l15) * D_;
    k00 = *(const bf16x8*)Kt0;
    k01 = *(const bf16x8*)(Kt0 + 32);
    k10 = *(const bf16x8*)(Kt0 + (size_t)16 * D_);
    k11 = *(const bf16x8*)(Kt0 + (size_t)16 * D_ + 32);
    const u16* Vt0 = Vb + klo;
    v0 = *(const bf16x8*)(Vt0);
    v1 = *(const bf16x8*)(Vt0 + (size_t)16 * VTS);
    v2 = *(const bf16x8*)(Vt0 + (size_t)32 * VTS);
    v3 = *(const bf16x8*)(Vt0 + (size_t)48 * VTS);
  }

  for (int k0 = klo;;) {
    const int kn = k0 + 32;
    const bool more = kn <= qw;   // last tile starts at k0 == qw (covers qw..qw+31)
    bf16x8 nk00, nk01, nk10, nk11, nv0, nv1, nv2, nv3;
    if (more) {
      const u16* Kt0 = Kb + (size_t)(kn + l15) * D_;
      nk00 = *(const bf16x8*)Kt0;
      nk01 = *(const bf16x8*)(Kt0 + 32);
      nk10 = *(const bf16x8*)(Kt0 + (size_t)16 * D_);
      nk11 = *(const bf16x8*)(Kt0 + (size_t)16 * D_ + 32);
      const u16* Vt0 = Vb + kn;
      nv0 = *(const bf16x8*)(Vt0);
      nv1 = *(const bf16x8*)(Vt0 + (size_t)16 * VTS);
      nv2 = *(const bf16x8*)(Vt0 + (size_t)32 * VTS);
      nv3 = *(const bf16x8*)(Vt0 + (size_t)48 * VTS);
    }

    // wave-uniform sub-tile activity for this k-tile
    const bool computeA = (k0 <= qw + 15);              // any key <= an A query
    const bool computeB = (k0 + 31 >= qwB - WIN_);      // any key in B's window

    if (computeA) {
      f32x4 s0 = {0.f, 0.f, 0.f, 0.f}, s1 = {0.f, 0.f, 0.f, 0.f};
      __builtin_amdgcn_s_setprio(1);
      s0 = MFMA(k00, aq0, s0);
      s0 = MFMA(k01, aq1, s0);
      s1 = MFMA(k10, aq0, s1);
      s1 = MFMA(k11, aq1, s1);
      __builtin_amdgcn_s_setprio(0);
      const bool interior = (k0 >= qw + 15 - WIN_) && (k0 + 31 <= qw);
      float e[8];
      if (interior) {
#pragma unroll
        for (int r = 0; r < 4; r++) {
          float p0 = __builtin_amdgcn_exp2f(s0[r]);
          float p1 = __builtin_amdgcn_exp2f(s1[r]);
          e[r] = p0; e[4 + r] = p1;
          lrA += p0 + p1;
        }
      } else {
#pragma unroll
        for (int r = 0; r < 4; r++) {
          int key0 = k0 + quad * 4 + r;
          int key1 = key0 + 16;
          float p0 = (key0 <= qA && key0 + WIN_ >= qA) ? __builtin_amdgcn_exp2f(s0[r]) : 0.f;
          float p1 = (key1 <= qA && key1 + WIN_ >= qA) ? __builtin_amdgcn_exp2f(s1[r]) : 0.f;
          e[r] = p0; e[4 + r] = p1;
          lrA += p0 + p1;
        }
      }
      unsigned int s0p01 = pkbf(e[0], e[1]);
      unsigned int s0p23 = pkbf(e[2], e[3]);
      unsigned int s1p01 = pkbf(e[4], e[5]);
      unsigned int s1p23 = pkbf(e[6], e[7]);
      unsigned int a0 = (unsigned)__shfl((int)s0p01, srcA);
      unsigned int a1 = (unsigned)__shfl((int)s0p23, srcA);
      unsigned int a2 = (unsigned)__shfl((int)s0p01, srcB);
      unsigned int a3 = (unsigned)__shfl((int)s0p23, srcB);
      unsigned int c0 = (unsigned)__shfl((int)s1p01, srcA);
      unsigned int c1 = (unsigned)__shfl((int)s1p23, srcA);
      unsigned int c2 = (unsigned)__shfl((int)s1p01, srcB);
      unsigned int c3 = (unsigned)__shfl((int)s1p23, srcB);
      union { unsigned int u[4]; bf16x8 v; } pf;
      const bool lo = quad < 2;
      pf.u[0] = lo ? a0 : c0;
      pf.u[1] = lo ? a1 : c1;
      pf.u[2] = lo ? a2 : c2;
      pf.u[3] = lo ? a3 : c3;
      __builtin_amdgcn_s_setprio(1);
      OA[0] = MFMA(v0, pf.v, OA[0]);
      OA[1] = MFMA(v1, pf.v, OA[1]);
      OA[2] = MFMA(v2, pf.v, OA[2]);
      OA[3] = MFMA(v3, pf.v, OA[3]);
      __builtin_amdgcn_s_setprio(0);
    }

    if (computeB) {
      f32x4 s0 = {0.f, 0.f, 0.f, 0.f}, s1 = {0.f, 0.f, 0.f, 0.f};
      __builtin_amdgcn_s_setprio(1);
      s0 = MFMA(k00, bq0, s0);
      s0 = MFMA(k01, bq1, s0);
      s1 = MFMA(k10, bq0, s1);
      s1 = MFMA(k11, bq1, s1);
      __builtin_amdgcn_s_setprio(0);
      const bool interior = (k0 >= qwB + 15 - WIN_) && (k0 + 31 <= qwB);
      float e[8];
      if (interior) {
#pragma unroll
        for (int r = 0; r < 4; r++) {
          float p0 = __builtin_amdgcn_exp2f(s0[r]);
          float p1 = __builtin_amdgcn_exp2f(s1[r]);
          e[r] = p0; e[4 + r] = p1;
          lrB += p0 + p1;
        }
      } else {
#pragma unroll
        for (int r = 0; r < 4; r++) {
          int key0 = k0 + quad * 4 + r;
          int key1 = key0 + 16;
          float p0 = (key0 <= qB && key0 + WIN_ >= qB) ? __builtin_amdgcn_exp2f(s0[r]) : 0.f;
          float p1 = (key1 <= qB && key1 + WIN_ >= qB) ? __builtin_amdgcn_exp2f(s1[r]) : 0.f;
          e[r] = p0; e[4 + r] = p1;
          lrB += p0 + p1;
        }
      }
      unsigned int s0p01 = pkbf(e[0], e[1]);
      unsigned int s0p23 = pkbf(e[2], e[3]);
      unsigned int s1p01 = pkbf(e[4], e[5]);
      unsigned int s1p23 = pkbf(e[6], e[7]);
      unsigned int a0 = (unsigned)__shfl((int)s0p01, srcA);
      unsigned int a1 = (unsigned)__shfl((int)s0p23, srcA);
      unsigned int a2 = (unsigned)__shfl((int)s0p01, srcB);
      unsigned int a3 = (unsigned)__shfl((int)s0p23, srcB);
      unsigned int c0 = (unsigned)__shfl((int)s1p01, srcA);
      unsigned int c1 = (unsigned)__shfl((int)s1p23, srcA);
      unsigned int c2 = (unsigned)__shfl((int)s1p01, srcB);
      unsigned int c3 = (unsigned)__shfl((int)s1p23, srcB);
      union { unsigned int u[4]; bf16x8 v; } pf;
      const bool lo = quad < 2;
      pf.u[0] = lo ? a0 : c0;
      pf.u[1] = lo ? a1 : c1;
      pf.u[2] = lo ? a2 : c2;
      pf.u[3] = lo ? a3 : c3;
      __builtin_amdgcn_s_setprio(1);
      OB[0] = MFMA(v0, pf.v, OB[0]);
      OB[1] = MFMA(v1, pf.v, OB[1]);
      OB[2] = MFMA(v2, pf.v, OB[2]);
      OB[3] = MFMA(v3, pf.v, OB[3]);
      __builtin_amdgcn_s_setprio(0);
    }

    if (!more) break;
    k00 = nk00; k01 = nk01; k10 = nk10; k11 = nk11;
    v0 = nv0; v1 = nv1; v2 = nv2; v3 = nv3;
    k0 = kn;
  }

  // per-quad partial sums -> full row sums (same l15 across quads)
  lrA += __shfl_xor(lrA, 16);
  lrA += __shfl_xor(lrA, 32);
  lrB += __shfl_xor(lrB, 16);
  lrB += __shfl_xor(lrB, 32);
  const float invA = 1.0f / lrA;
  const float invB = 1.0f / lrB;

  // epilogue: 32 rows per wave (A -> rows 0..15, B -> rows 16..31)
  u16* P = &Plds[w][0];
#pragma unroll
  for (int j = 0; j < 4; j++)
#pragma unroll
    for (int r = 0; r < 4; r++) {
      P[l15 * 72 + j * 16 + quad * 4 + r] = f2b(OA[j][r] * invA);
      P[(l15 + 16) * 72 + j * 16 + quad * 4 + r] = f2b(OB[j][r] * invB);
    }
#pragma unroll
  for (int it = 0; it < 2; it++) {
    int rq = (lane >> 2) + it * 16, cc = lane & 3;
    bf16x8 ov0 = *(const bf16x8*)&P[rq * 72 + cc * 16];
    bf16x8 ov1 = *(const bf16x8*)&P[rq * 72 + cc * 16 + 8];
    u16* dst = Ab + (size_t)(b_ * S_ + qw + rq) * D_ + h * DH_ + cc * 16;
    *(bf16x8*)dst = ov0;
    *(bf16x8*)(dst + 8) = ov1;
  }
}

extern "C" void kernel_launch(void* const* d_in, const int* in_sizes, int n_in,
                              void* d_out, int out_size, void* d_ws, size_t ws_size,
                              hipStream_t stream) {
  const float* x  = (const float*)d_in[0];
  const float* wq = (const float*)d_in[1];
  const float* bq = (const float*)d_in[2];
  const float* wk = (const float*)d_in[3];
  const float* bk = (const float*)d_in[4];
  const float* wv = (const float*)d_in[5];
  const float* bv = (const float*)d_in[6];
  const float* wo = (const float*)d_in[7];
  const float* bo = (const float*)d_in[8];

  char* ws = (char*)d_ws;
  const size_t MB = 1u << 20;
  u16* Qg    = (u16*)(ws + 0 * MB);    // 8 MB [B,S,D] bf16, pre-scaled
  u16* Kg    = (u16*)(ws + 8 * MB);    // 8 MB [B,S,D]
  u16* Vt    = (u16*)(ws + 16 * MB);   // 9 MB [B,H,DH,VTS] (padded stride)
  u16* Ab    = (u16*)(ws + 25 * MB);   // 8 MB [B,S,D] attention output
  u16* xb    = (u16*)(ws + 33 * MB);   // 8 MB [B*S,D]
  u16* wqkvt = (u16*)(ws + 41 * MB);   // 6 MB [3072][1024] transposed bf16
  u16* wot   = (u16*)(ws + 47 * MB);   // 2 MB [1024][1024] transposed bf16

  k_prep<<<2048, 256, 0, stream>>>(x, wq, wk, wv, wo, xb, wqkvt, wot);
  k_gemm_qkv<<<768, 256, 0, stream>>>(xb, wqkvt, bq, bk, bv, Qg, Kg, Vt);
  k_attn<<<512, 256, 0, stream>>>(Qg, Kg, Vt, Ab);
  k_gemm_out<<<512, 256, 0, stream>>>(Ab, wot, bo, (float*)d_out);
}

// Round 17
// 153.210 us; speedup vs baseline: 1.0671x; 1.0003x over previous
//
#include <hip/hip_runtime.h>

#define B_ 2
#define S_ 2048
#define D_ 1024
#define H_ 16
#define DH_ 64
#define WIN_ 256
#define VTS 2080   // Vt row stride (elements): 4KB+64B breaks L1 set-aliasing

typedef __attribute__((ext_vector_type(8))) short bf16x8;
typedef __attribute__((ext_vector_type(4))) float f32x4;
typedef unsigned short u16;

#define MFMA(a, b, c) __builtin_amdgcn_mfma_f32_16x16x32_bf16((a), (b), (c), 0, 0, 0)

__device__ __forceinline__ u16 f2b(float f) {
  unsigned int u = __float_as_uint(f);
  u += 0x7fffu + ((u >> 16) & 1u);
  return (u16)(u >> 16);
}

__device__ __forceinline__ float b2f(u16 b) {
  return __uint_as_float(((unsigned int)b) << 16);
}

// RTNE pack of two f32 into packed bf16x2 — single VALU op (kept from R21, neutral).
__device__ __forceinline__ unsigned int pkbf(float lo, float hi) {
  unsigned int r;
  asm("v_cvt_pk_bf16_f32 %0, %1, %2" : "=v"(r) : "v"(lo), "v"(hi));
  return r;
}

__device__ __forceinline__ void async_cp16(const void* g, void* l) {
  __builtin_amdgcn_global_load_lds(
      (const __attribute__((address_space(1))) void*)g,
      (__attribute__((address_space(3))) void*)l, 16, 0, 0);
}

// ------- prep: x fp32->bf16 convert (grid-stride) + weight transpose -------
__global__ void k_prep(const float* __restrict__ x,
                       const float* __restrict__ wq, const float* __restrict__ wk,
                       const float* __restrict__ wv, const float* __restrict__ wo,
                       u16* __restrict__ xb, u16* __restrict__ wqkvt, u16* __restrict__ wot) {
  __shared__ float tile[64][65];
  const int bx = blockIdx.x;
  const int t = threadIdx.x;
  if (bx < 1024) {
    const int t0 = (bx * 256 + t) * 4;
#pragma unroll
    for (int it = 0; it < 4; it++) {
      int i = t0 + it * 1048576;   // 1024 blocks * 256 thr * 4 elem
      float4 v = *(const float4*)(x + i);
      ushort4 o;
      o.x = f2b(v.x); o.y = f2b(v.y); o.z = f2b(v.z); o.w = f2b(v.w);
      *(ushort4*)(xb + i) = o;
    }
    return;
  }
  const int tb = bx - 1024;
  const int z = tb >> 8, rest = tb & 255;
  const float* W = z == 0 ? wq : z == 1 ? wk : z == 2 ? wv : wo;
  u16* T = z < 3 ? wqkvt + (size_t)z * 1024 * 1024 : wot;
  const int bn = (rest & 15) * 64;   // col block of W = row block of T
  const int bk = (rest >> 4) * 64;   // row block of W
  const int r = t >> 4;
  const int c = (t & 15) * 4;
#pragma unroll
  for (int i = 0; i < 4; i++) {
    float4 v = *(const float4*)(W + (size_t)(bk + r + i * 16) * D_ + bn + c);
    tile[c + 0][r + i * 16] = v.x;
    tile[c + 1][r + i * 16] = v.y;
    tile[c + 2][r + i * 16] = v.z;
    tile[c + 3][r + i * 16] = v.w;
  }
  __syncthreads();
  const int n = t >> 2, seg = (t & 3) * 16;
  __align__(16) u16 tmp[16];
#pragma unroll
  for (int u = 0; u < 16; u++) tmp[u] = f2b(tile[n][seg + u]);
  uint4* dst = (uint4*)(T + (size_t)(bn + n) * D_ + bk + seg);
  dst[0] = ((uint4*)tmp)[0];
  dst[1] = ((uint4*)tmp)[1];
}

// -------- fused QKV GEMM over N=3072; Q,K -> [B,S,D]; V -> [B,H,DH,VTS] --------
// R24: T3/T4 minimum pipeline — double-buffered LDS + raw s_barrier + COUNTED
// vmcnt(8). Tile t+1's 8 global_load_lds stay in flight across the barrier while
// tile t computes; the wait is only for tile t's loads. This targets the measured
// 12.6us cold-load exposure (qkv: 32.6us cold vs 20us warm, R4). LDS 64KB ->
// 2 blocks/CU (was 3): pipeline must beat the lost cross-block overlap.
__global__ __launch_bounds__(256, 2) void k_gemm_qkv(
    const u16* __restrict__ xb, const u16* __restrict__ wqkvt,
    const float* __restrict__ bq, const float* __restrict__ bk_, const float* __restrict__ bv,
    u16* __restrict__ Qg, u16* __restrict__ Kg, u16* __restrict__ Vt) {
  __shared__ __align__(16) u16 smem[32768];   // 64KB: buf0=[0,16384) buf1=[16384,32768)
                                              // each buf: As(8192) + Bs(8192); epilogue reuses buf0
  const int L = blockIdx.x;
  const int xcd = L & 7, slot = L >> 3;            // slot 0..95
  const int mblk = (xcd >> 1) * 8 + (slot & 7);    // 0..31
  const int nblk = (xcd & 1) * 12 + (slot >> 3);   // 0..23
  const int n0 = nblk * 128, m0 = mblk * 128;
  const int z = n0 >> 10;
  const float* bias = z == 0 ? bq : z == 1 ? bk_ : bv;

  const int tid = threadIdx.x;
  const int w = tid >> 6, lane = tid & 63;
  const int quad = lane >> 4, l15 = lane & 15;
  const int wm = (w & 1) * 64, wn = (w >> 1) * 64;
  const int rowa = tid >> 3;                       // 0..31
  const int colsw = (((tid & 7) ^ (rowa & 7)) * 8);
  const u16* ap = xb + (size_t)(m0 + rowa) * D_ + colsw;
  const u16* bp = wqkvt + (size_t)(n0 + rowa) * D_ + colsw;
  const int c0 = ((quad * 8) ^ ((l15 & 7) * 8));
  f32x4 acc[4][4] = {};

  // stage tile (K offset kb) into buffer buf: 8 gload_lds per wave
#define STAGE(kb, buf)                                                            \
  {                                                                               \
    u16* As0 = smem + (buf)*16384 + w * 512;                                      \
    u16* Bs0 = smem + (buf)*16384 + 8192 + w * 512;                               \
    _Pragma("unroll")                                                             \
    for (int i = 0; i < 4; i++) {                                                 \
      async_cp16(ap + (kb) + (size_t)(i * 32) * D_, As0 + i * 2048);              \
      async_cp16(bp + (kb) + (size_t)(i * 32) * D_, Bs0 + i * 2048);              \
    }                                                                             \
  }

#define COMPUTE(buf)                                                              \
  {                                                                               \
    const u16* As = smem + (buf)*16384;                                           \
    const u16* Bs = smem + (buf)*16384 + 8192;                                    \
    _Pragma("unroll")                                                             \
    for (int kh = 0; kh < 2; kh++) {                                              \
      const int c = c0 ^ (kh * 32);                                               \
      bf16x8 af[4], bfr[4];                                                       \
      _Pragma("unroll")                                                           \
      for (int i = 0; i < 4; i++) af[i] = *(const bf16x8*)&As[(wm + i * 16 + l15) * 64 + c]; \
      _Pragma("unroll")                                                           \
      for (int j = 0; j < 4; j++) bfr[j] = *(const bf16x8*)&Bs[(wn + j * 16 + l15) * 64 + c]; \
      _Pragma("unroll")                                                           \
      for (int i = 0; i < 4; i++)                                                 \
        _Pragma("unroll")                                                         \
        for (int j = 0; j < 4; j++) acc[i][j] = MFMA(af[i], bfr[j], acc[i][j]);   \
    }                                                                             \
  }

  STAGE(0, 0);
  // 15 pipelined steps: stage t+1, wait only tile t's loads (8 newer stay in flight)
  for (int t = 0; t < 15; ++t) {
    const int cur = t & 1;
    STAGE((t + 1) * 64, cur ^ 1);
    asm volatile("s_waitcnt vmcnt(8)" ::: "memory");
    __builtin_amdgcn_s_barrier();
    COMPUTE(cur);
    __builtin_amdgcn_s_barrier();
  }
  // last tile (t=15, cur=1): drain remaining 8 loads
  asm volatile("s_waitcnt vmcnt(0)" ::: "memory");
  __builtin_amdgcn_s_barrier();
  COMPUTE(1);
  __syncthreads();   // full drain before epilogue reuses buf0 LDS
#undef STAGE
#undef COMPUTE

  const int nloc = n0 & 1023;
  float biasv[4];
#pragma unroll
  for (int j = 0; j < 4; j++) biasv[j] = bias[nloc + wn + j * 16 + l15];
  const int b_ = m0 >> 11, sb = m0 & 2047;
  // Q pre-scale folds 1/sqrt(DH) and log2(e) so attention uses raw exp2.
  const float scale = z == 0 ? 0.125f * 1.44269504f : 1.0f;
  const int row = tid >> 4, ch = tid & 15;

  if (z < 2) {
    // C-layout -> LDS (padded stride 136) -> coalesced row-major store
#pragma unroll
    for (int j = 0; j < 4; j++)
#pragma unroll
      for (int i = 0; i < 4; i++)
#pragma unroll
        for (int r = 0; r < 4; r++)
          smem[(wm + i * 16 + quad * 4 + r) * 136 + wn + j * 16 + l15] =
              f2b((acc[i][j][r] + biasv[j]) * scale);
    __syncthreads();
    u16* OG = z == 0 ? Qg : Kg;
#pragma unroll
    for (int it = 0; it < 8; it++) {
      int rr = row + it * 16;
      bf16x8 v = *(const bf16x8*)&smem[rr * 136 + ch * 8];
      *(bf16x8*)(OG + (size_t)(m0 + rr) * D_ + nloc + ch * 8) = v;
    }
  } else {
    // write transposed into LDS: Ct[n_local][m_local]
#pragma unroll
    for (int j = 0; j < 4; j++)
#pragma unroll
      for (int i = 0; i < 4; i++)
#pragma unroll
        for (int r = 0; r < 4; r++)
          smem[(wn + j * 16 + l15) * 136 + wm + i * 16 + quad * 4 + r] =
              f2b(acc[i][j][r] + biasv[j]);
    __syncthreads();
#pragma unroll
    for (int it = 0; it < 8; it++) {
      int nn = nloc + row + it * 16;
      int h = nn >> 6, dh = nn & 63;
      bf16x8 v = *(const bf16x8*)&smem[(row + it * 16) * 136 + ch * 8];
      *(bf16x8*)(Vt + ((size_t)(b_ * H_ + h) * DH_ + dh) * VTS + sb + ch * 8) = v;
    }
  }
}

// ---------- output projection: 64x128 tiles, BK=128 (32 MFMA/barrier) ----------
__global__ __launch_bounds__(256, 2) void k_gemm_out(
    const u16* __restrict__ Ab, const u16* __restrict__ wot,
    const float* __restrict__ bo, float* __restrict__ out) {
  __shared__ __align__(16) u16 smem[24576];   // A 64x128 + B 128x128; epilogue 64x136
  u16* As = smem;
  u16* Bs = smem + 8192;
  const int L = blockIdx.x;
  const int xcd = L & 7, slot = L >> 3;        // slot 0..63
  const int mblk = xcd * 8 + (slot & 7);       // 0..63
  const int nblk = slot >> 3;                  // 0..7
  const int n0 = nblk * 128, m0 = mblk * 64;
  const int tid = threadIdx.x;
  const int w = tid >> 6, lane = tid & 63;
  const int quad = lane >> 4, l15 = lane & 15;
  const int wn = w * 32;
  const int rowa = tid >> 4;                   // 0..15
  const int gg = (tid & 15) ^ rowa;
  const u16* ap = Ab + (size_t)(m0 + rowa) * D_ + gg * 8;
  const u16* bp = wot + (size_t)(n0 + rowa) * D_ + gg * 8;
  u16* As0 = As + w * 512;
  u16* Bs0 = Bs + w * 512;
  f32x4 acc[4][2] = {};
  for (int kb = 0; kb < D_; kb += 128) {
#pragma unroll
    for (int i = 0; i < 4; i++)
      async_cp16(ap + kb + (size_t)(i * 16) * D_, As0 + i * 2048);
#pragma unroll
    for (int i = 0; i < 8; i++)
      async_cp16(bp + kb + (size_t)(i * 16) * D_, Bs0 + i * 2048);
    __syncthreads();
#pragma unroll
    for (int kh = 0; kh < 4; kh++) {
      const int cs = (((quad + 4 * kh) ^ l15) * 8);
      bf16x8 af[4], bfr[2];
#pragma unroll
      for (int i = 0; i < 4; i++) af[i] = *(const bf16x8*)&As[(i * 16 + l15) * 128 + cs];
#pragma unroll
      for (int j = 0; j < 2; j++) bfr[j] = *(const bf16x8*)&Bs[(wn + j * 16 + l15) * 128 + cs];
#pragma unroll
      for (int i = 0; i < 4; i++)
#pragma unroll
        for (int j = 0; j < 2; j++) acc[i][j] = MFMA(af[i], bfr[j], acc[i][j]);
    }
    __syncthreads();
  }
  float biasv[2];
#pragma unroll
  for (int j = 0; j < 2; j++) biasv[j] = bo[n0 + wn + j * 16 + l15];
#pragma unroll
  for (int j = 0; j < 2; j++)
#pragma unroll
    for (int i = 0; i < 4; i++)
#pragma unroll
      for (int r = 0; r < 4; r++)
        smem[(i * 16 + quad * 4 + r) * 136 + wn + j * 16 + l15] = f2b(acc[i][j][r] + biasv[j]);
  __syncthreads();
  const int row = tid >> 4, ch = tid & 15;
#pragma unroll
  for (int it = 0; it < 4; it++) {
    int rr = row + it * 16;
    bf16x8 v = *(const bf16x8*)&smem[rr * 136 + ch * 8];
    float4 f0, f1;
    f0.x = b2f((u16)v[0]); f0.y = b2f((u16)v[1]); f0.z = b2f((u16)v[2]); f0.w = b2f((u16)v[3]);
    f1.x = b2f((u16)v[4]); f1.y = b2f((u16)v[5]); f1.z = b2f((u16)v[6]); f1.w = b2f((u16)v[7]);
    float* dst = out + (size_t)(m0 + rr) * D_ + n0 + ch * 8;
    *(float4*)dst = f0;
    *(float4*)(dst + 4) = f1;
  }
}

// ---------------- windowed flash attention, QBLK=32 per wave ----------------
// R18 (validated): 32 queries/wave as two 16-query sub-tiles sharing one K/V walk.
// R15 XCD pinning kept; R21 cvt_pk pack kept (neutral, shorter).
__global__ __launch_bounds__(256, 2) void k_attn(
    const u16* __restrict__ Qg, const u16* __restrict__ Kg,
    const u16* __restrict__ Vt, u16* __restrict__ Ab) {
  __shared__ __align__(16) u16 Plds[4][32 * 72];
  const int tid = threadIdx.x;
  const int w = tid >> 6, lane = tid & 63;
  const int quad = lane >> 4, l15 = lane & 15;
  const int lid = blockIdx.x;
  const int xcd = lid & 7, slot = lid >> 3;   // slot 0..63
  const int bh = xcd * 4 + (slot & 3);        // 4 bh per XCD
  const int qb = slot >> 2;                   // 0..15
  const int qw = qb * 128 + w * 32;           // wave's 32-query base (mult of 32)
  const int b_ = bh >> 4, h = bh & 15;

  // Q fragments: sub-tile A = queries qw+l15, B = qw+16+l15 (pre-scaled)
  const u16* QbaseA = Qg + (size_t)(b_ * S_ + qw + l15) * D_ + h * DH_ + quad * 8;
  bf16x8 aq0 = *(const bf16x8*)QbaseA;
  bf16x8 aq1 = *(const bf16x8*)(QbaseA + 32);
  const u16* QbaseB = QbaseA + (size_t)16 * D_;
  bf16x8 bq0 = *(const bf16x8*)QbaseB;
  bf16x8 bq1 = *(const bf16x8*)(QbaseB + 32);

  float lrA = 0.f, lrB = 0.f;
  f32x4 OA[4] = {}, OB[4] = {};

  const u16* Kb = Kg + (size_t)b_ * S_ * D_ + h * DH_ + quad * 8;
  const u16* Vb = Vt + (size_t)bh * DH_ * VTS + (size_t)l15 * VTS + quad * 8;
  const int klo = qw >= WIN_ ? qw - WIN_ : 0;   // qw mult of 32 -> aligned
  const int qA = qw + l15, qB = qA + 16;
  const int qwB = qw + 16;
  const int srcA = l15 + ((quad & 1) ? 32 : 0);
  const int srcB = srcA + 16;

  bf16x8 k00, k01, k10, k11, v0, v1, v2, v3;
  {
    const u16* Kt0 = Kb + (size_t)(klo + l15) * D_;
    k00 = *(const bf16x8*)Kt0;
    k01 = *(const bf16x8*)(Kt0 + 32);
    k10 = *(const bf16x8*)(Kt0 + (size_t)16 * D_);
    k11 = *(const bf16x8*)(Kt0 + (size_t)16 * D_ + 32);
    const u16* Vt0 = Vb + klo;
    v0 = *(const bf16x8*)(Vt0);
    v1 = *(const bf16x8*)(Vt0 + (size_t)16 * VTS);
    v2 = *(const bf16x8*)(Vt0 + (size_t)32 * VTS);
    v3 = *(const bf16x8*)(Vt0 + (size_t)48 * VTS);
  }

  for (int k0 = klo;;) {
    const int kn = k0 + 32;
    const bool more = kn <= qw;   // last tile starts at k0 == qw (covers qw..qw+31)
    bf16x8 nk00, nk01, nk10, nk11, nv0, nv1, nv2, nv3;
    if (more) {
      const u16* Kt0 = Kb + (size_t)(kn + l15) * D_;
      nk00 = *(const bf16x8*)Kt0;
      nk01 = *(const bf16x8*)(Kt0 + 32);
      nk10 = *(const bf16x8*)(Kt0 + (size_t)16 * D_);
      nk11 = *(const bf16x8*)(Kt0 + (size_t)16 * D_ + 32);
      const u16* Vt0 = Vb + kn;
      nv0 = *(const bf16x8*)(Vt0);
      nv1 = *(const bf16x8*)(Vt0 + (size_t)16 * VTS);
      nv2 = *(const bf16x8*)(Vt0 + (size_t)32 * VTS);
      nv3 = *(const bf16x8*)(Vt0 + (size_t)48 * VTS);
    }

    // wave-uniform sub-tile activity for this k-tile
    const bool computeA = (k0 <= qw + 15);              // any key <= an A query
    const bool computeB = (k0 + 31 >= qwB - WIN_);      // any key in B's window

    if (computeA) {
      f32x4 s0 = {0.f, 0.f, 0.f, 0.f}, s1 = {0.f, 0.f, 0.f, 0.f};
      __builtin_amdgcn_s_setprio(1);
      s0 = MFMA(k00, aq0, s0);
      s0 = MFMA(k01, aq1, s0);
      s1 = MFMA(k10, aq0, s1);
      s1 = MFMA(k11, aq1, s1);
      __builtin_amdgcn_s_setprio(0);
      const bool interior = (k0 >= qw + 15 - WIN_) && (k0 + 31 <= qw);
      float e[8];
      if (interior) {
#pragma unroll
        for (int r = 0; r < 4; r++) {
          float p0 = __builtin_amdgcn_exp2f(s0[r]);
          float p1 = __builtin_amdgcn_exp2f(s1[r]);
          e[r] = p0; e[4 + r] = p1;
          lrA += p0 + p1;
        }
      } else {
#pragma unroll
        for (int r = 0; r < 4; r++) {
          int key0 = k0 + quad * 4 + r;
          int key1 = key0 + 16;
          float p0 = (key0 <= qA && key0 + WIN_ >= qA) ? __builtin_amdgcn_exp2f(s0[r]) : 0.f;
          float p1 = (key1 <= qA && key1 + WIN_ >= qA) ? __builtin_amdgcn_exp2f(s1[r]) : 0.f;
          e[r] = p0; e[4 + r] = p1;
          lrA += p0 + p1;
        }
      }
      unsigned int s0p01 = pkbf(e[0], e[1]);
      unsigned int s0p23 = pkbf(e[2], e[3]);
      unsigned int s1p01 = pkbf(e[4], e[5]);
      unsigned int s1p23 = pkbf(e[6], e[7]);
      unsigned int a0 = (unsigned)__shfl((int)s0p01, srcA);
      unsigned int a1 = (unsigned)__shfl((int)s0p23, srcA);
      unsigned int a2 = (unsigned)__shfl((int)s0p01, srcB);
      unsigned int a3 = (unsigned)__shfl((int)s0p23, srcB);
      unsigned int c0 = (unsigned)__shfl((int)s1p01, srcA);
      unsigned int c1 = (unsigned)__shfl((int)s1p23, srcA);
      unsigned int c2 = (unsigned)__shfl((int)s1p01, srcB);
      unsigned int c3 = (unsigned)__shfl((int)s1p23, srcB);
      union { unsigned int u[4]; bf16x8 v; } pf;
      const bool lo = quad < 2;
      pf.u[0] = lo ? a0 : c0;
      pf.u[1] = lo ? a1 : c1;
      pf.u[2] = lo ? a2 : c2;
      pf.u[3] = lo ? a3 : c3;
      __builtin_amdgcn_s_setprio(1);
      OA[0] = MFMA(v0, pf.v, OA[0]);
      OA[1] = MFMA(v1, pf.v, OA[1]);
      OA[2] = MFMA(v2, pf.v, OA[2]);
      OA[3] = MFMA(v3, pf.v, OA[3]);
      __builtin_amdgcn_s_setprio(0);
    }

    if (computeB) {
      f32x4 s0 = {0.f, 0.f, 0.f, 0.f}, s1 = {0.f, 0.f, 0.f, 0.f};
      __builtin_amdgcn_s_setprio(1);
      s0 = MFMA(k00, bq0, s0);
      s0 = MFMA(k01, bq1, s0);
      s1 = MFMA(k10, bq0, s1);
      s1 = MFMA(k11, bq1, s1);
      __builtin_amdgcn_s_setprio(0);
      const bool interior = (k0 >= qwB + 15 - WIN_) && (k0 + 31 <= qwB);
      float e[8];
      if (interior) {
#pragma unroll
        for (int r = 0; r < 4; r++) {
          float p0 = __builtin_amdgcn_exp2f(s0[r]);
          float p1 = __builtin_amdgcn_exp2f(s1[r]);
          e[r] = p0; e[4 + r] = p1;
          lrB += p0 + p1;
        }
      } else {
#pragma unroll
        for (int r = 0; r < 4; r++) {
          int key0 = k0 + quad * 4 + r;
          int key1 = key0 + 16;
          float p0 = (key0 <= qB && key0 + WIN_ >= qB) ? __builtin_amdgcn_exp2f(s0[r]) : 0.f;
          float p1 = (key1 <= qB && key1 + WIN_ >= qB) ? __builtin_amdgcn_exp2f(s1[r]) : 0.f;
          e[r] = p0; e[4 + r] = p1;
          lrB += p0 + p1;
        }
      }
      unsigned int s0p01 = pkbf(e[0], e[1]);
      unsigned int s0p23 = pkbf(e[2], e[3]);
      unsigned int s1p01 = pkbf(e[4], e[5]);
      unsigned int s1p23 = pkbf(e[6], e[7]);
      unsigned int a0 = (unsigned)__shfl((int)s0p01, srcA);
      unsigned int a1 = (unsigned)__shfl((int)s0p23, srcA);
      unsigned int a2 = (unsigned)__shfl((int)s0p01, srcB);
      unsigned int a3 = (unsigned)__shfl((int)s0p23, srcB);
      unsigned int c0 = (unsigned)__shfl((int)s1p01, srcA);
      unsigned int c1 = (unsigned)__shfl((int)s1p23, srcA);
      unsigned int c2 = (unsigned)__shfl((int)s1p01, srcB);
      unsigned int c3 = (unsigned)__shfl((int)s1p23, srcB);
      union { unsigned int u[4]; bf16x8 v; } pf;
      const bool lo = quad < 2;
      pf.u[0] = lo ? a0 : c0;
      pf.u[1] = lo ? a1 : c1;
      pf.u[2] = lo ? a2 : c2;
      pf.u[3] = lo ? a3 : c3;
      __builtin_amdgcn_s_setprio(1);
      OB[0] = MFMA(v0, pf.v, OB[0]);
      OB[1] = MFMA(v1, pf.v, OB[1]);
      OB[2] = MFMA(v2, pf.v, OB[2]);
      OB[3] = MFMA(v3, pf.v, OB[3]);
      __builtin_amdgcn_s_setprio(0);
    }

    if (!more) break;
    k00 = nk00; k01 = nk01; k10 = nk10; k11 = nk11;
    v0 = nv0; v1 = nv1; v2 = nv2; v3 = nv3;
    k0 = kn;
  }

  // per-quad partial sums -> full row sums (same l15 across quads)
  lrA += __shfl_xor(lrA, 16);
  lrA += __shfl_xor(lrA, 32);
  lrB += __shfl_xor(lrB, 16);
  lrB += __shfl_xor(lrB, 32);
  const float invA = 1.0f / lrA;
  const float invB = 1.0f / lrB;

  // epilogue: 32 rows per wave (A -> rows 0..15, B -> rows 16..31)
  u16* P = &Plds[w][0];
#pragma unroll
  for (int j = 0; j < 4; j++)
#pragma unroll
    for (int r = 0; r < 4; r++) {
      P[l15 * 72 + j * 16 + quad * 4 + r] = f2b(OA[j][r] * invA);
      P[(l15 + 16) * 72 + j * 16 + quad * 4 + r] = f2b(OB[j][r] * invB);
    }
#pragma unroll
  for (int it = 0; it < 2; it++) {
    int rq = (lane >> 2) + it * 16, cc = lane & 3;
    bf16x8 ov0 = *(const bf16x8*)&P[rq * 72 + cc * 16];
    bf16x8 ov1 = *(const bf16x8*)&P[rq * 72 + cc * 16 + 8];
    u16* dst = Ab + (size_t)(b_ * S_ + qw + rq) * D_ + h * DH_ + cc * 16;
    *(bf16x8*)dst = ov0;
    *(bf16x8*)(dst + 8) = ov1;
  }
}

extern "C" void kernel_launch(void* const* d_in, const int* in_sizes, int n_in,
                              void* d_out, int out_size, void* d_ws, size_t ws_size,
                              hipStream_t stream) {
  const float* x  = (const float*)d_in[0];
  const float* wq = (const float*)d_in[1];
  const float* bq = (const float*)d_in[2];
  const float* wk = (const float*)d_in[3];
  const float* bk = (const float*)d_in[4];
  const float* wv = (const float*)d_in[5];
  const float* bv = (const float*)d_in[6];
  const float* wo = (const float*)d_in[7];
  const float* bo = (const float*)d_in[8];

  char* ws = (char*)d_ws;
  const size_t MB = 1u << 20;
  u16* Qg    = (u16*)(ws + 0 * MB);    // 8 MB [B,S,D] bf16, pre-scaled
  u16* Kg    = (u16*)(ws + 8 * MB);    // 8 MB [B,S,D]
  u16* Vt    = (u16*)(ws + 16 * MB);   // 9 MB [B,H,DH,VTS] (padded stride)
  u16* Ab    = (u16*)(ws + 25 * MB);   // 8 MB [B,S,D] attention output
  u16* xb    = (u16*)(ws + 33 * MB);   // 8 MB [B*S,D]
  u16* wqkvt = (u16*)(ws + 41 * MB);   // 6 MB [3072][1024] transposed bf16
  u16* wot   = (u16*)(ws + 47 * MB);   // 2 MB [1024][1024] transposed bf16

  k_prep<<<2048, 256, 0, stream>>>(x, wq, wk, wv, wo, xb, wqkvt, wot);
  k_gemm_qkv<<<768, 256, 0, stream>>>(xb, wqkvt, bq, bk, bv, Qg, Kg, Vt);
  k_attn<<<512, 256, 0, stream>>>(Qg, Kg, Vt, Ab);
  k_gemm_out<<<512, 256, 0, stream>>>(Ab, wot, bo, (float*)d_out);
}